// Round 1
// baseline (559.728 us; speedup 1.0000x reference)
//
#include <hip/hip_runtime.h>
#include <hip/hip_bf16.h>

#ifndef BN_EPS
#define BN_EPS 1e-5f
#endif

// ---------------------------------------------------------------------------
// Problem shape: N=100000 nodes, C=64 channels, E=1600000 edges.
// Pipeline:
//   deg[dst]++  ->  dinv = rsqrt(deg+1)  ->  h = x@W (+ self-loop init of out)
//   -> scatter: out[dst] += dinv[src]*dinv[dst]*h[src]  (fp32 HW atomics)
//   -> BN stats (mean/var per channel) -> BN apply + ReLU
// bias cancels exactly inside BatchNorm (constant per-channel shift), skipped.
// ---------------------------------------------------------------------------

__global__ __launch_bounds__(256) void k_deg(const int* __restrict__ dst,
                                             int* __restrict__ deg, int E) {
    int i = blockIdx.x * 256 + threadIdx.x;
    if (i < E) atomicAdd(&deg[dst[i]], 1);
}

__global__ __launch_bounds__(256) void k_dinv(const int* __restrict__ deg,
                                              float* __restrict__ dinv, int n) {
    int i = blockIdx.x * 256 + threadIdx.x;
    if (i < n) dinv[i] = rsqrtf((float)(deg[i] + 1));  // +1 = self-loop
}

// h = x @ W  (W 64x64 staged in LDS, x row in registers),
// out initialized with the self-loop term dinv^2 * h (full write, no zeroing).
__global__ __launch_bounds__(256) void k_gemm(const float* __restrict__ x,
                                              const float* __restrict__ W,
                                              const float* __restrict__ dinv,
                                              float* __restrict__ h,
                                              float* __restrict__ out, int n) {
    __shared__ float Ws[64 * 64];
    for (int i = threadIdx.x; i < 64 * 64; i += 256) Ws[i] = W[i];
    __syncthreads();
    int r = blockIdx.x * 256 + threadIdx.x;
    if (r >= n) return;

    float xr[64];
    const float4* xp = (const float4*)(x + (size_t)r * 64);
#pragma unroll
    for (int i = 0; i < 16; i++) ((float4*)xr)[i] = xp[i];

    float d2 = dinv[r] * dinv[r];
    float4* hp = (float4*)(h + (size_t)r * 64);
    float4* op = (float4*)(out + (size_t)r * 64);

#pragma unroll
    for (int c4 = 0; c4 < 16; c4++) {
        float4 acc = {0.f, 0.f, 0.f, 0.f};
#pragma unroll
        for (int k = 0; k < 64; k++) {
            float xv = xr[k];
            acc.x = fmaf(xv, Ws[k * 64 + c4 * 4 + 0], acc.x);
            acc.y = fmaf(xv, Ws[k * 64 + c4 * 4 + 1], acc.y);
            acc.z = fmaf(xv, Ws[k * 64 + c4 * 4 + 2], acc.z);
            acc.w = fmaf(xv, Ws[k * 64 + c4 * 4 + 3], acc.w);
        }
        hp[c4] = acc;
        float4 o = {acc.x * d2, acc.y * d2, acc.z * d2, acc.w * d2};
        op[c4] = o;
    }
}

// One wave per edge, lane = channel. Edge indices staged through LDS so the
// per-edge index/norm reads are wave-uniform LDS broadcasts.
__global__ __launch_bounds__(256) void k_scatter(const int* __restrict__ src,
                                                 const int* __restrict__ dst,
                                                 const float* __restrict__ h,
                                                 const float* __restrict__ dinv,
                                                 float* __restrict__ out, int E) {
    __shared__ int s_src[64];
    __shared__ int s_dst[64];
    __shared__ float s_norm[64];
    int base = blockIdx.x * 64;
    int tid = threadIdx.x;
    if (tid < 64) {
        int e = base + tid;
        s_src[tid] = (e < E) ? src[e] : 0;
    } else if (tid < 128) {
        int t = tid - 64;
        int e = base + t;
        s_dst[t] = (e < E) ? dst[e] : 0;
    }
    __syncthreads();
    if (tid < 64) s_norm[tid] = dinv[s_src[tid]] * dinv[s_dst[tid]];
    __syncthreads();

    int wave = tid >> 6;
    int lane = tid & 63;
#pragma unroll
    for (int j = 0; j < 16; j++) {
        int i = wave * 16 + j;
        int e = base + i;
        if (e >= E) break;
        int s = s_src[i];
        int d = s_dst[i];
        float v = h[(size_t)s * 64 + lane] * s_norm[i];
        unsafeAtomicAdd(&out[(size_t)d * 64 + lane], v);
    }
}

// Per-channel sum & sum-of-squares. Grid stride (in elements) is a multiple of
// 64, so each thread's 4-channel group is fixed; wave shuffle-reduce (lanes
// l, l+16, l+32, l+48 share a group), then LDS, then global atomics.
__global__ __launch_bounds__(256) void k_stats(const float* __restrict__ out,
                                               float* __restrict__ stats,
                                               int total4) {
    __shared__ float s_sum[64];
    __shared__ float s_sq[64];
    if (threadIdx.x < 64) {
        s_sum[threadIdx.x] = 0.f;
        s_sq[threadIdx.x] = 0.f;
    }
    __syncthreads();

    int idx = blockIdx.x * 256 + threadIdx.x;
    int stride = gridDim.x * 256;  // *4 elements => multiple of 64 channels
    const float4* p = (const float4*)out;
    float4 sum = {0.f, 0.f, 0.f, 0.f};
    float4 sq = {0.f, 0.f, 0.f, 0.f};
    for (int i = idx; i < total4; i += stride) {
        float4 v = p[i];
        sum.x += v.x; sum.y += v.y; sum.z += v.z; sum.w += v.w;
        sq.x = fmaf(v.x, v.x, sq.x);
        sq.y = fmaf(v.y, v.y, sq.y);
        sq.z = fmaf(v.z, v.z, sq.z);
        sq.w = fmaf(v.w, v.w, sq.w);
    }
#pragma unroll
    for (int off = 16; off < 64; off <<= 1) {
        sum.x += __shfl_xor(sum.x, off);
        sum.y += __shfl_xor(sum.y, off);
        sum.z += __shfl_xor(sum.z, off);
        sum.w += __shfl_xor(sum.w, off);
        sq.x += __shfl_xor(sq.x, off);
        sq.y += __shfl_xor(sq.y, off);
        sq.z += __shfl_xor(sq.z, off);
        sq.w += __shfl_xor(sq.w, off);
    }
    int lane = threadIdx.x & 63;
    if (lane < 16) {
        int cg = (idx * 4) & 63;  // channel base for this thread (fixed)
        atomicAdd(&s_sum[cg + 0], sum.x);
        atomicAdd(&s_sum[cg + 1], sum.y);
        atomicAdd(&s_sum[cg + 2], sum.z);
        atomicAdd(&s_sum[cg + 3], sum.w);
        atomicAdd(&s_sq[cg + 0], sq.x);
        atomicAdd(&s_sq[cg + 1], sq.y);
        atomicAdd(&s_sq[cg + 2], sq.z);
        atomicAdd(&s_sq[cg + 3], sq.w);
    }
    __syncthreads();
    if (threadIdx.x < 64) {
        atomicAdd(&stats[threadIdx.x], s_sum[threadIdx.x]);
    } else if (threadIdx.x < 128) {
        atomicAdd(&stats[threadIdx.x], s_sq[threadIdx.x - 64]);
    }
}

__global__ void k_bnprep(const float* __restrict__ stats,
                         const float* __restrict__ gamma,
                         const float* __restrict__ beta,
                         float* __restrict__ ss, float invN) {
    int c = threadIdx.x;  // 64 threads
    float mean = stats[c] * invN;
    float var = stats[64 + c] * invN - mean * mean;  // biased var, matches ref
    float scale = gamma[c] * rsqrtf(var + BN_EPS);
    ss[c] = scale;
    ss[64 + c] = beta[c] - mean * scale;
}

__global__ __launch_bounds__(256) void k_bn(float* __restrict__ out,
                                            const float* __restrict__ ss,
                                            int total4) {
    int idx = blockIdx.x * 256 + threadIdx.x;
    int stride = gridDim.x * 256;
    int cg = (idx * 4) & 63;  // fixed per thread (stride*4 % 64 == 0)
    float sc0 = ss[cg + 0], sc1 = ss[cg + 1], sc2 = ss[cg + 2], sc3 = ss[cg + 3];
    float sh0 = ss[64 + cg + 0], sh1 = ss[64 + cg + 1];
    float sh2 = ss[64 + cg + 2], sh3 = ss[64 + cg + 3];
    float4* p = (float4*)out;
    for (int i = idx; i < total4; i += stride) {
        float4 v = p[i];
        v.x = fmaxf(fmaf(v.x, sc0, sh0), 0.f);
        v.y = fmaxf(fmaf(v.y, sc1, sh1), 0.f);
        v.z = fmaxf(fmaf(v.z, sc2, sh2), 0.f);
        v.w = fmaxf(fmaf(v.w, sc3, sh3), 0.f);
        p[i] = v;
    }
}

extern "C" void kernel_launch(void* const* d_in, const int* in_sizes, int n_in,
                              void* d_out, int out_size, void* d_ws, size_t ws_size,
                              hipStream_t stream) {
    const float* x = (const float*)d_in[0];
    const int* ei = (const int*)d_in[1];   // harness delivers ints as int32
    const float* W = (const float*)d_in[2];
    // d_in[3] = bias: cancels inside BatchNorm, unused.
    const float* gamma = (const float*)d_in[4];
    const float* beta = (const float*)d_in[5];
    float* out = (float*)d_out;

    const int N = in_sizes[0] / 64;
    const int E = in_sizes[1] / 2;
    const int* src = ei;
    const int* dst = ei + E;

    char* ws = (char*)d_ws;
    int* deg = (int*)ws;                                   // N ints
    float* stats = (float*)(ws + (size_t)N * 4);           // 128 floats
    float* ss = (float*)(ws + (size_t)N * 4 + 512);        // 128 floats
    float* dinv = (float*)(ws + (size_t)N * 4 + 1024);     // N floats
    float* h = (float*)(ws + (size_t)N * 8 + 1024);        // N*64 floats

    // zero deg + stats (+ss, harmless)
    hipMemsetAsync(ws, 0, (size_t)N * 4 + 1024, stream);

    k_deg<<<(E + 255) / 256, 256, 0, stream>>>(dst, deg, E);
    k_dinv<<<(N + 255) / 256, 256, 0, stream>>>(deg, dinv, N);
    k_gemm<<<(N + 255) / 256, 256, 0, stream>>>(x, W, dinv, h, out, N);
    k_scatter<<<(E + 63) / 64, 256, 0, stream>>>(src, dst, h, dinv, out, E);

    int total4 = N * 16;  // N*64/4
    k_stats<<<1024, 256, 0, stream>>>(out, stats, total4);
    k_bnprep<<<1, 64, 0, stream>>>(stats, gamma, beta, ss, 1.0f / (float)N);
    k_bn<<<1024, 256, 0, stream>>>(out, ss, total4);
}

// Round 2
// 445.844 us; speedup vs baseline: 1.2554x; 1.2554x over previous
//
#include <hip/hip_runtime.h>
#include <hip/hip_bf16.h>

#ifndef BN_EPS
#define BN_EPS 1e-5f
#endif

// ---------------------------------------------------------------------------
// N=100000 nodes, C=64, E=1600000 edges.
// R2: replace fp32 atomic scatter (atomic-unit bound, 1.25 TB/s write ceiling,
// 327us) with counting-sort -> CSR -> per-node gather-reduce (no fp atomics):
//   deg[dst]++ -> dinv=rsqrt(deg+1) -> exclusive scan(deg)=offs -> CSR fill
//   -> h = x@W -> per-node: out[n] = dinv[n]*(dinv[n]*h[n] + sum dinv[s]*h[s])
//   (BN partial stats fused into the aggregation epilogue)
//   -> bnprep -> BN apply + ReLU
// bias cancels inside BatchNorm, skipped.
// ---------------------------------------------------------------------------

__global__ __launch_bounds__(256) void k_deg(const int* __restrict__ dst,
                                             int* __restrict__ deg, int E) {
    int i = blockIdx.x * 256 + threadIdx.x;
    if (i < E) atomicAdd(&deg[dst[i]], 1);
}

__global__ __launch_bounds__(256) void k_dinv(const int* __restrict__ deg,
                                              float* __restrict__ dinv, int n) {
    int i = blockIdx.x * 256 + threadIdx.x;
    if (i < n) dinv[i] = rsqrtf((float)(deg[i] + 1));  // +1 = self-loop
}

// ---- 3-kernel exclusive scan of deg[N] -> offs[N] (and cur[N] copy) --------
__global__ __launch_bounds__(256) void k_scan1(const int* __restrict__ deg,
                                               int* __restrict__ part, int N) {
    __shared__ int s[256];
    int tid = threadIdx.x;
    int i = blockIdx.x * 256 + tid;
    s[tid] = (i < N) ? deg[i] : 0;
    __syncthreads();
    for (int off = 128; off > 0; off >>= 1) {
        if (tid < off) s[tid] += s[tid + off];
        __syncthreads();
    }
    if (tid == 0) part[blockIdx.x] = s[0];
}

__global__ __launch_bounds__(512) void k_scan2(const int* __restrict__ part,
                                               int* __restrict__ base, int NB) {
    __shared__ int s[512];
    int t = threadIdx.x;
    int v = (t < NB) ? part[t] : 0;
    s[t] = v;
    __syncthreads();
    for (int off = 1; off < 512; off <<= 1) {
        int add = (t >= off) ? s[t - off] : 0;
        __syncthreads();
        s[t] += add;
        __syncthreads();
    }
    if (t < NB) base[t] = s[t] - v;  // exclusive
}

__global__ __launch_bounds__(256) void k_scan3(const int* __restrict__ deg,
                                               const int* __restrict__ base,
                                               int* __restrict__ offs,
                                               int* __restrict__ cur, int N) {
    __shared__ int s[256];
    int tid = threadIdx.x;
    int i = blockIdx.x * 256 + tid;
    int v = (i < N) ? deg[i] : 0;
    s[tid] = v;
    __syncthreads();
    for (int off = 1; off < 256; off <<= 1) {
        int add = (tid >= off) ? s[tid - off] : 0;
        __syncthreads();
        s[tid] += add;
        __syncthreads();
    }
    if (i < N) {
        int excl = s[tid] - v + base[blockIdx.x];
        offs[i] = excl;
        cur[i] = excl;
    }
}

// CSR fill: csr[pos] = src, pos allocated with int atomics on per-node cursor.
__global__ __launch_bounds__(256) void k_fill(const int* __restrict__ src,
                                              const int* __restrict__ dst,
                                              int* __restrict__ cur,
                                              int* __restrict__ csr, int E) {
    int e = blockIdx.x * 256 + threadIdx.x;
    if (e < E) {
        int pos = atomicAdd(&cur[dst[e]], 1);
        csr[pos] = src[e];
    }
}

// h = x @ W  (W 64x64 staged in LDS, x row in registers).
__global__ __launch_bounds__(256) void k_gemm(const float* __restrict__ x,
                                              const float* __restrict__ W,
                                              float* __restrict__ h, int n) {
    __shared__ float Ws[64 * 64];
    for (int i = threadIdx.x; i < 64 * 64; i += 256) Ws[i] = W[i];
    __syncthreads();
    int r = blockIdx.x * 256 + threadIdx.x;
    if (r >= n) return;

    float xr[64];
    const float4* xp = (const float4*)(x + (size_t)r * 64);
#pragma unroll
    for (int i = 0; i < 16; i++) ((float4*)xr)[i] = xp[i];

    float4* hp = (float4*)(h + (size_t)r * 64);
#pragma unroll
    for (int c4 = 0; c4 < 16; c4++) {
        float4 acc = {0.f, 0.f, 0.f, 0.f};
#pragma unroll
        for (int k = 0; k < 64; k++) {
            float xv = xr[k];
            acc.x = fmaf(xv, Ws[k * 64 + c4 * 4 + 0], acc.x);
            acc.y = fmaf(xv, Ws[k * 64 + c4 * 4 + 1], acc.y);
            acc.z = fmaf(xv, Ws[k * 64 + c4 * 4 + 2], acc.z);
            acc.w = fmaf(xv, Ws[k * 64 + c4 * 4 + 3], acc.w);
        }
        hp[c4] = acc;
    }
}

// One wave per node (grid-stride over nodes): lanes = 64 channels.
// acc = dinv[n]*h[n]; for each in-edge s: acc += dinv[s]*h[s]; out = acc*dinv[n].
// Edge indices read coalesced in 64-chunks, broadcast via shfl.
// BN partial stats (sum, sumsq per channel) fused into the epilogue.
__global__ __launch_bounds__(256) void k_agg(const int* __restrict__ offs,
                                             const int* __restrict__ cur,
                                             const int* __restrict__ csr,
                                             const float* __restrict__ h,
                                             const float* __restrict__ dinv,
                                             float* __restrict__ out,
                                             float* __restrict__ stats, int N) {
    __shared__ float s_sum[64];
    __shared__ float s_sq[64];
    if (threadIdx.x < 64) {
        s_sum[threadIdx.x] = 0.f;
        s_sq[threadIdx.x] = 0.f;
    }
    __syncthreads();

    int lane = threadIdx.x & 63;
    int wid = (blockIdx.x * 256 + threadIdx.x) >> 6;
    int nw = (gridDim.x * 256) >> 6;
    float psum = 0.f, psq = 0.f;

    for (int n = wid; n < N; n += nw) {
        float dn = dinv[n];
        float acc = h[(size_t)n * 64 + lane] * dn;  // self-loop term
        int j0 = offs[n];
        int j1 = cur[n];  // == offs[n] + deg[n] after fill
        for (int jb = j0; jb < j1; jb += 64) {
            int cnt = min(64, j1 - jb);
            int idx = 0;
            float w = 0.f;
            if (lane < cnt) {
                idx = csr[jb + lane];
                w = dinv[idx];
            }
            for (int j = 0; j < cnt; j++) {
                int s = __shfl(idx, j);
                float ws = __shfl(w, j);
                acc = fmaf(ws, h[(size_t)s * 64 + lane], acc);
            }
        }
        float o = acc * dn;
        out[(size_t)n * 64 + lane] = o;
        psum += o;
        psq = fmaf(o, o, psq);
    }

    atomicAdd(&s_sum[lane], psum);
    atomicAdd(&s_sq[lane], psq);
    __syncthreads();
    if (threadIdx.x < 64) {
        atomicAdd(&stats[threadIdx.x], s_sum[threadIdx.x]);
    } else if (threadIdx.x < 128) {
        atomicAdd(&stats[threadIdx.x], s_sq[threadIdx.x - 64]);
    }
}

__global__ void k_bnprep(const float* __restrict__ stats,
                         const float* __restrict__ gamma,
                         const float* __restrict__ beta,
                         float* __restrict__ ss, float invN) {
    int c = threadIdx.x;  // 64 threads
    float mean = stats[c] * invN;
    float var = stats[64 + c] * invN - mean * mean;  // biased var, matches ref
    float scale = gamma[c] * rsqrtf(var + BN_EPS);
    ss[c] = scale;
    ss[64 + c] = beta[c] - mean * scale;
}

__global__ __launch_bounds__(256) void k_bn(float* __restrict__ out,
                                            const float* __restrict__ ss,
                                            int total4) {
    int idx = blockIdx.x * 256 + threadIdx.x;
    int stride = gridDim.x * 256;
    int cg = (idx * 4) & 63;  // fixed per thread (stride*4 % 64 == 0)
    float sc0 = ss[cg + 0], sc1 = ss[cg + 1], sc2 = ss[cg + 2], sc3 = ss[cg + 3];
    float sh0 = ss[64 + cg + 0], sh1 = ss[64 + cg + 1];
    float sh2 = ss[64 + cg + 2], sh3 = ss[64 + cg + 3];
    float4* p = (float4*)out;
    for (int i = idx; i < total4; i += stride) {
        float4 v = p[i];
        v.x = fmaxf(fmaf(v.x, sc0, sh0), 0.f);
        v.y = fmaxf(fmaf(v.y, sc1, sh1), 0.f);
        v.z = fmaxf(fmaf(v.z, sc2, sh2), 0.f);
        v.w = fmaxf(fmaf(v.w, sc3, sh3), 0.f);
        p[i] = v;
    }
}

extern "C" void kernel_launch(void* const* d_in, const int* in_sizes, int n_in,
                              void* d_out, int out_size, void* d_ws, size_t ws_size,
                              hipStream_t stream) {
    const float* x = (const float*)d_in[0];
    const int* ei = (const int*)d_in[1];
    const float* W = (const float*)d_in[2];
    // d_in[3] = bias: cancels inside BatchNorm, unused.
    const float* gamma = (const float*)d_in[4];
    const float* beta = (const float*)d_in[5];
    float* out = (float*)d_out;

    const int N = in_sizes[0] / 64;
    const int E = in_sizes[1] / 2;
    const int* src = ei;
    const int* dst = ei + E;
    const int NB = (N + 255) / 256;  // 391 for N=100000 (<=512 required)

    char* ws = (char*)d_ws;
    int* deg = (int*)ws;                           // N ints
    int* offs = (int*)(ws + (size_t)4 * N);        // N ints
    int* cur = (int*)(ws + (size_t)8 * N);         // N ints
    float* dinv = (float*)(ws + (size_t)12 * N);   // N floats
    int* part = (int*)(ws + (size_t)16 * N);       // 512 ints
    int* base = (int*)(ws + (size_t)16 * N + 2048);// 512 ints
    float* stats = (float*)(ws + (size_t)16 * N + 4096);  // 128 floats
    float* ss = (float*)(ws + (size_t)16 * N + 4608);     // 128 floats
    float* h = (float*)(ws + (size_t)16 * N + 8192);      // N*64 floats
    int* csr = (int*)(ws + (size_t)16 * N + 8192 + (size_t)256 * N);  // E ints

    // zero deg; zero stats
    hipMemsetAsync(deg, 0, (size_t)N * 4, stream);
    hipMemsetAsync(stats, 0, 512, stream);

    k_deg<<<(E + 255) / 256, 256, 0, stream>>>(dst, deg, E);
    k_dinv<<<(N + 255) / 256, 256, 0, stream>>>(deg, dinv, N);
    k_scan1<<<NB, 256, 0, stream>>>(deg, part, N);
    k_scan2<<<1, 512, 0, stream>>>(part, base, NB);
    k_scan3<<<NB, 256, 0, stream>>>(deg, base, offs, cur, N);
    k_fill<<<(E + 255) / 256, 256, 0, stream>>>(src, dst, cur, csr, E);
    k_gemm<<<(N + 255) / 256, 256, 0, stream>>>(x, W, h, N);
    k_agg<<<2048, 256, 0, stream>>>(offs, cur, csr, h, dinv, out, stats, N);
    k_bnprep<<<1, 64, 0, stream>>>(stats, gamma, beta, ss, 1.0f / (float)N);
    k_bn<<<1024, 256, 0, stream>>>(out, ss, N * 16);
}

// Round 3
// 381.413 us; speedup vs baseline: 1.4675x; 1.1689x over previous
//
#include <hip/hip_runtime.h>
#include <hip/hip_bf16.h>

#ifndef BN_EPS
#define BN_EPS 1e-5f
#endif

// ---------------------------------------------------------------------------
// N=100000, C=64, E=1600000.
// R3: aggregate-then-GEMM (linearity swap) + bf16 gather operand.
//   pre:  deg[dst]++  AND  xb = bf16(x)                (fused, one pass)
//   scan: offs = exclusive_scan(deg), cur = offs, dinv = rsqrt(deg+1)
//   fill: csr counting-sort by dst
//   agg:  aggb[n] = bf16( dinv[n]*(dinv[n]*xb[n] + sum_s dinv[s]*xb[s]) )
//         (wave per node, lane=channel, bf16 gather halves fetch bytes)
//   gemm: out = aggb @ W   (fp32 accumulate, thread per row, W in LDS)
//   stats -> bnprep -> BN+ReLU in place.
// bias cancels inside BatchNorm, skipped.
// ---------------------------------------------------------------------------

__device__ __forceinline__ unsigned short f2bf(float f) {
    unsigned u = __float_as_uint(f);
    u += 0x7FFF + ((u >> 16) & 1);  // round-to-nearest-even
    return (unsigned short)(u >> 16);
}
__device__ __forceinline__ float bf2f(unsigned v) {
    return __uint_as_float(v << 16);
}

// deg count (int atomics) + x -> bf16 conversion, fused.
__global__ __launch_bounds__(256) void k_pre(const float* __restrict__ x,
                                             const int* __restrict__ dst,
                                             int* __restrict__ deg,
                                             unsigned short* __restrict__ xb,
                                             int E, int n4) {
    int i = blockIdx.x * 256 + threadIdx.x;
    if (i < E) atomicAdd(&deg[dst[i]], 1);
    if (i < n4) {
        float4 v = ((const float4*)x)[i];
        ushort4 b;
        b.x = f2bf(v.x); b.y = f2bf(v.y); b.z = f2bf(v.z); b.w = f2bf(v.w);
        ((ushort4*)xb)[i] = b;
    }
}

// ---- exclusive scan of deg[N] -> offs/cur, fused dinv ----------------------
__global__ __launch_bounds__(256) void k_scan1(const int* __restrict__ deg,
                                               int* __restrict__ part, int N) {
    __shared__ int s[256];
    int tid = threadIdx.x;
    int i = blockIdx.x * 256 + tid;
    s[tid] = (i < N) ? deg[i] : 0;
    __syncthreads();
    for (int off = 128; off > 0; off >>= 1) {
        if (tid < off) s[tid] += s[tid + off];
        __syncthreads();
    }
    if (tid == 0) part[blockIdx.x] = s[0];
}

__global__ __launch_bounds__(512) void k_scan2(const int* __restrict__ part,
                                               int* __restrict__ base, int NB) {
    __shared__ int s[512];
    int t = threadIdx.x;
    int v = (t < NB) ? part[t] : 0;
    s[t] = v;
    __syncthreads();
    for (int off = 1; off < 512; off <<= 1) {
        int add = (t >= off) ? s[t - off] : 0;
        __syncthreads();
        s[t] += add;
        __syncthreads();
    }
    if (t < NB) base[t] = s[t] - v;  // exclusive
}

__global__ __launch_bounds__(256) void k_scan3(const int* __restrict__ deg,
                                               const int* __restrict__ base,
                                               int* __restrict__ offs,
                                               int* __restrict__ cur,
                                               float* __restrict__ dinv, int N) {
    __shared__ int s[256];
    int tid = threadIdx.x;
    int i = blockIdx.x * 256 + tid;
    int v = (i < N) ? deg[i] : 0;
    s[tid] = v;
    __syncthreads();
    for (int off = 1; off < 256; off <<= 1) {
        int add = (tid >= off) ? s[tid - off] : 0;
        __syncthreads();
        s[tid] += add;
        __syncthreads();
    }
    if (i < N) {
        int excl = s[tid] - v + base[blockIdx.x];
        offs[i] = excl;
        cur[i] = excl;
        dinv[i] = rsqrtf((float)(v + 1));  // +1 = self-loop
    }
}

__global__ __launch_bounds__(256) void k_fill(const int* __restrict__ src,
                                              const int* __restrict__ dst,
                                              int* __restrict__ cur,
                                              int* __restrict__ csr, int E) {
    int e = blockIdx.x * 256 + threadIdx.x;
    if (e < E) {
        int pos = atomicAdd(&cur[dst[e]], 1);
        csr[pos] = src[e];
    }
}

// Wave per node, lane = channel. bf16 gather, fp32 accumulate, bf16 store.
// 4x unrolled inner loop keeps 4 independent gathers in flight.
__global__ __launch_bounds__(256) void k_agg(const int* __restrict__ offs,
                                             const int* __restrict__ cur,
                                             const int* __restrict__ csr,
                                             const unsigned short* __restrict__ xb,
                                             const float* __restrict__ dinv,
                                             unsigned short* __restrict__ aggb,
                                             int N) {
    int lane = threadIdx.x & 63;
    int wid = (blockIdx.x * 256 + threadIdx.x) >> 6;
    int nw = (gridDim.x * 256) >> 6;

    for (int n = wid; n < N; n += nw) {
        float dn = dinv[n];
        float acc = bf2f(xb[(size_t)n * 64 + lane]) * dn;  // self-loop term
        int j0 = offs[n];
        int j1 = cur[n];  // == offs[n] + deg[n]
        for (int jb = j0; jb < j1; jb += 64) {
            int cnt = min(64, j1 - jb);
            int idx = 0;
            float w = 0.f;
            if (lane < cnt) {
                idx = csr[jb + lane];
                w = dinv[idx];
            }
            int j = 0;
            for (; j + 4 <= cnt; j += 4) {
                int s0 = __shfl(idx, j + 0), s1 = __shfl(idx, j + 1);
                int s2 = __shfl(idx, j + 2), s3 = __shfl(idx, j + 3);
                float w0 = __shfl(w, j + 0), w1 = __shfl(w, j + 1);
                float w2 = __shfl(w, j + 2), w3 = __shfl(w, j + 3);
                float v0 = bf2f(xb[(size_t)s0 * 64 + lane]);
                float v1 = bf2f(xb[(size_t)s1 * 64 + lane]);
                float v2 = bf2f(xb[(size_t)s2 * 64 + lane]);
                float v3 = bf2f(xb[(size_t)s3 * 64 + lane]);
                acc = fmaf(w0, v0, acc);
                acc = fmaf(w1, v1, acc);
                acc = fmaf(w2, v2, acc);
                acc = fmaf(w3, v3, acc);
            }
            for (; j < cnt; j++) {
                int s = __shfl(idx, j);
                float ws = __shfl(w, j);
                acc = fmaf(ws, bf2f(xb[(size_t)s * 64 + lane]), acc);
            }
        }
        aggb[(size_t)n * 64 + lane] = f2bf(acc * dn);
    }
}

// out = aggb @ W, thread per row, fp32 accumulate (W staged in LDS).
__global__ __launch_bounds__(256) void k_gemm(const unsigned short* __restrict__ aggb,
                                              const float* __restrict__ W,
                                              float* __restrict__ out, int n) {
    __shared__ float Ws[64 * 64];
    for (int i = threadIdx.x; i < 64 * 64; i += 256) Ws[i] = W[i];
    __syncthreads();
    int r = blockIdx.x * 256 + threadIdx.x;
    if (r >= n) return;

    float a[64];
    const uint4* ap = (const uint4*)(aggb + (size_t)r * 64);
#pragma unroll
    for (int i = 0; i < 8; i++) {
        uint4 q = ap[i];
        a[i * 8 + 0] = bf2f(q.x & 0xFFFFu); a[i * 8 + 1] = bf2f(q.x >> 16);
        a[i * 8 + 2] = bf2f(q.y & 0xFFFFu); a[i * 8 + 3] = bf2f(q.y >> 16);
        a[i * 8 + 4] = bf2f(q.z & 0xFFFFu); a[i * 8 + 5] = bf2f(q.z >> 16);
        a[i * 8 + 6] = bf2f(q.w & 0xFFFFu); a[i * 8 + 7] = bf2f(q.w >> 16);
    }

    float4* op = (float4*)(out + (size_t)r * 64);
#pragma unroll
    for (int c4 = 0; c4 < 16; c4++) {
        float4 acc = {0.f, 0.f, 0.f, 0.f};
#pragma unroll
        for (int k = 0; k < 64; k++) {
            float xv = a[k];
            acc.x = fmaf(xv, Ws[k * 64 + c4 * 4 + 0], acc.x);
            acc.y = fmaf(xv, Ws[k * 64 + c4 * 4 + 1], acc.y);
            acc.z = fmaf(xv, Ws[k * 64 + c4 * 4 + 2], acc.z);
            acc.w = fmaf(xv, Ws[k * 64 + c4 * 4 + 3], acc.w);
        }
        op[c4] = acc;
    }
}

// Per-channel sum & sumsq of out.
__global__ __launch_bounds__(256) void k_stats(const float* __restrict__ out,
                                               float* __restrict__ stats,
                                               int total4) {
    __shared__ float s_sum[64];
    __shared__ float s_sq[64];
    if (threadIdx.x < 64) {
        s_sum[threadIdx.x] = 0.f;
        s_sq[threadIdx.x] = 0.f;
    }
    __syncthreads();

    int idx = blockIdx.x * 256 + threadIdx.x;
    int stride = gridDim.x * 256;  // *4 elems => multiple of 64 channels
    const float4* p = (const float4*)out;
    float4 sum = {0.f, 0.f, 0.f, 0.f};
    float4 sq = {0.f, 0.f, 0.f, 0.f};
    for (int i = idx; i < total4; i += stride) {
        float4 v = p[i];
        sum.x += v.x; sum.y += v.y; sum.z += v.z; sum.w += v.w;
        sq.x = fmaf(v.x, v.x, sq.x);
        sq.y = fmaf(v.y, v.y, sq.y);
        sq.z = fmaf(v.z, v.z, sq.z);
        sq.w = fmaf(v.w, v.w, sq.w);
    }
#pragma unroll
    for (int off = 16; off < 64; off <<= 1) {
        sum.x += __shfl_xor(sum.x, off);
        sum.y += __shfl_xor(sum.y, off);
        sum.z += __shfl_xor(sum.z, off);
        sum.w += __shfl_xor(sum.w, off);
        sq.x += __shfl_xor(sq.x, off);
        sq.y += __shfl_xor(sq.y, off);
        sq.z += __shfl_xor(sq.z, off);
        sq.w += __shfl_xor(sq.w, off);
    }
    int lane = threadIdx.x & 63;
    if (lane < 16) {
        int cg = (idx * 4) & 63;
        atomicAdd(&s_sum[cg + 0], sum.x);
        atomicAdd(&s_sum[cg + 1], sum.y);
        atomicAdd(&s_sum[cg + 2], sum.z);
        atomicAdd(&s_sum[cg + 3], sum.w);
        atomicAdd(&s_sq[cg + 0], sq.x);
        atomicAdd(&s_sq[cg + 1], sq.y);
        atomicAdd(&s_sq[cg + 2], sq.z);
        atomicAdd(&s_sq[cg + 3], sq.w);
    }
    __syncthreads();
    if (threadIdx.x < 64) {
        atomicAdd(&stats[threadIdx.x], s_sum[threadIdx.x]);
    } else if (threadIdx.x < 128) {
        atomicAdd(&stats[threadIdx.x], s_sq[threadIdx.x - 64]);
    }
}

__global__ void k_bnprep(const float* __restrict__ stats,
                         const float* __restrict__ gamma,
                         const float* __restrict__ beta,
                         float* __restrict__ ss, float invN) {
    int c = threadIdx.x;  // 64 threads
    float mean = stats[c] * invN;
    float var = stats[64 + c] * invN - mean * mean;  // biased var
    float scale = gamma[c] * rsqrtf(var + BN_EPS);
    ss[c] = scale;
    ss[64 + c] = beta[c] - mean * scale;
}

__global__ __launch_bounds__(256) void k_bn(float* __restrict__ out,
                                            const float* __restrict__ ss,
                                            int total4) {
    int idx = blockIdx.x * 256 + threadIdx.x;
    int stride = gridDim.x * 256;
    int cg = (idx * 4) & 63;
    float sc0 = ss[cg + 0], sc1 = ss[cg + 1], sc2 = ss[cg + 2], sc3 = ss[cg + 3];
    float sh0 = ss[64 + cg + 0], sh1 = ss[64 + cg + 1];
    float sh2 = ss[64 + cg + 2], sh3 = ss[64 + cg + 3];
    float4* p = (float4*)out;
    for (int i = idx; i < total4; i += stride) {
        float4 v = p[i];
        v.x = fmaxf(fmaf(v.x, sc0, sh0), 0.f);
        v.y = fmaxf(fmaf(v.y, sc1, sh1), 0.f);
        v.z = fmaxf(fmaf(v.z, sc2, sh2), 0.f);
        v.w = fmaxf(fmaf(v.w, sc3, sh3), 0.f);
        p[i] = v;
    }
}

extern "C" void kernel_launch(void* const* d_in, const int* in_sizes, int n_in,
                              void* d_out, int out_size, void* d_ws, size_t ws_size,
                              hipStream_t stream) {
    const float* x = (const float*)d_in[0];
    const int* ei = (const int*)d_in[1];
    const float* W = (const float*)d_in[2];
    // d_in[3] = bias: cancels inside BatchNorm, unused.
    const float* gamma = (const float*)d_in[4];
    const float* beta = (const float*)d_in[5];
    float* out = (float*)d_out;

    const int N = in_sizes[0] / 64;
    const int E = in_sizes[1] / 2;
    const int* src = ei;
    const int* dst = ei + E;
    const int NB = (N + 255) / 256;  // 391 (<=512 required by k_scan2)

    char* ws = (char*)d_ws;
    int* deg = (int*)ws;                                    // [0, 4N)
    float* stats = (float*)(ws + (size_t)4 * N);            // 512 B
    float* ss = (float*)(ws + (size_t)4 * N + 512);         // 512 B
    int* part = (int*)(ws + (size_t)4 * N + 1024);          // 2048 B
    int* base = (int*)(ws + (size_t)4 * N + 3072);          // 2048 B
    int* offs = (int*)(ws + (size_t)4 * N + 5120);          // 4N
    int* cur = (int*)(ws + (size_t)8 * N + 5120);           // 4N
    float* dinv = (float*)(ws + (size_t)12 * N + 5120);     // 4N
    unsigned short* xb = (unsigned short*)(ws + (size_t)16 * N + 5120);    // 128N
    unsigned short* aggb = (unsigned short*)(ws + (size_t)144 * N + 5120); // 128N
    int* csr = (int*)(ws + (size_t)272 * N + 5120);         // 4E

    // zero deg + stats (contiguous)
    hipMemsetAsync(deg, 0, (size_t)4 * N + 512, stream);

    int n4 = N * 16;  // float4 groups in x
    int preN = (E > n4) ? E : n4;
    k_pre<<<(preN + 255) / 256, 256, 0, stream>>>(x, dst, deg, xb, E, n4);
    k_scan1<<<NB, 256, 0, stream>>>(deg, part, N);
    k_scan2<<<1, 512, 0, stream>>>(part, base, NB);
    k_scan3<<<NB, 256, 0, stream>>>(deg, base, offs, cur, dinv, N);
    k_fill<<<(E + 255) / 256, 256, 0, stream>>>(src, dst, cur, csr, E);
    k_agg<<<2048, 256, 0, stream>>>(offs, cur, csr, xb, dinv, aggb, N);
    k_gemm<<<(N + 255) / 256, 256, 0, stream>>>(aggb, W, out, N);
    k_stats<<<1024, 256, 0, stream>>>(out, stats, N * 16);
    k_bnprep<<<1, 64, 0, stream>>>(stats, gamma, beta, ss, 1.0f / (float)N);
    k_bn<<<1024, 256, 0, stream>>>(out, ss, N * 16);
}

// Round 4
// 342.839 us; speedup vs baseline: 1.6326x; 1.1125x over previous
//
#include <hip/hip_runtime.h>
#include <hip/hip_bf16.h>

#ifndef BN_EPS
#define BN_EPS 1e-5f
#endif

// ---------------------------------------------------------------------------
// N=100000, C=64, E=1600000.
// R4: (a) XCD-affine CSR fill: 13-bucket binning (8192-node dst ranges) with
//     LDS chunk-sort -> coalesced binned[] runs; then per-bucket local fill
//     whose 512KB csr window stays in ONE XCD's L2 (blockIdx%8 heuristic) ->
//     single writeback instead of 105MB of cross-XCD partial line writebacks.
//     (b) paired-edge gather in k_agg: lane=(half,chanpair), one 4B load
//     serves 2 edges; halves combined by shfl_xor(32) at the end.
// Pipeline: pre(deg+bf16) -> scan(offs,dinv,bucket bases) -> bin -> fillL
//           -> agg(bf16) -> gemm -> stats -> bnprep -> bn+relu.
// bias cancels inside BatchNorm, skipped.
// ---------------------------------------------------------------------------

#define NPB 8192
#define NPB_SHIFT 13

__device__ __forceinline__ unsigned short f2bf(float f) {
    unsigned u = __float_as_uint(f);
    u += 0x7FFF + ((u >> 16) & 1);  // round-to-nearest-even
    return (unsigned short)(u >> 16);
}
__device__ __forceinline__ float bf2f(unsigned v) {
    return __uint_as_float(v << 16);
}

// deg count (int atomics) + x -> bf16 conversion, fused.
__global__ __launch_bounds__(256) void k_pre(const float* __restrict__ x,
                                             const int* __restrict__ dst,
                                             int* __restrict__ deg,
                                             unsigned short* __restrict__ xb,
                                             int E, int n4) {
    int i = blockIdx.x * 256 + threadIdx.x;
    if (i < E) atomicAdd(&deg[dst[i]], 1);
    if (i < n4) {
        float4 v = ((const float4*)x)[i];
        ushort4 b;
        b.x = f2bf(v.x); b.y = f2bf(v.y); b.z = f2bf(v.z); b.w = f2bf(v.w);
        ((ushort4*)xb)[i] = b;
    }
}

// ---- exclusive scan of deg[N] -> offs/cur, fused dinv + bucket bases -------
__global__ __launch_bounds__(256) void k_scan1(const int* __restrict__ deg,
                                               int* __restrict__ part, int N) {
    __shared__ int s[256];
    int tid = threadIdx.x;
    int i = blockIdx.x * 256 + tid;
    s[tid] = (i < N) ? deg[i] : 0;
    __syncthreads();
    for (int off = 128; off > 0; off >>= 1) {
        if (tid < off) s[tid] += s[tid + off];
        __syncthreads();
    }
    if (tid == 0) part[blockIdx.x] = s[0];
}

__global__ __launch_bounds__(512) void k_scan2(const int* __restrict__ part,
                                               int* __restrict__ base, int NB) {
    __shared__ int s[512];
    int t = threadIdx.x;
    int v = (t < NB) ? part[t] : 0;
    s[t] = v;
    __syncthreads();
    for (int off = 1; off < 512; off <<= 1) {
        int add = (t >= off) ? s[t - off] : 0;
        __syncthreads();
        s[t] += add;
        __syncthreads();
    }
    if (t < NB) base[t] = s[t] - v;  // exclusive
}

__global__ __launch_bounds__(256) void k_scan3(const int* __restrict__ deg,
                                               const int* __restrict__ base,
                                               int* __restrict__ offs,
                                               int* __restrict__ cur,
                                               float* __restrict__ dinv,
                                               int* __restrict__ bbase,
                                               int* __restrict__ bcur, int N) {
    __shared__ int s[256];
    int tid = threadIdx.x;
    int i = blockIdx.x * 256 + tid;
    int v = (i < N) ? deg[i] : 0;
    s[tid] = v;
    __syncthreads();
    for (int off = 1; off < 256; off <<= 1) {
        int add = (tid >= off) ? s[tid - off] : 0;
        __syncthreads();
        s[tid] += add;
        __syncthreads();
    }
    if (i < N) {
        int excl = s[tid] - v + base[blockIdx.x];
        offs[i] = excl;
        cur[i] = excl;
        dinv[i] = rsqrtf((float)(v + 1));  // +1 = self-loop
        if ((i & (NPB - 1)) == 0) {
            bbase[i >> NPB_SHIFT] = excl;
            bcur[i >> NPB_SHIFT] = excl;
        }
    }
}

// Chunked 13-bucket counting sort: binned[] filled in coalesced runs.
// packed entry = src (bits 0-16) | local_dst (bits 17-29).
__global__ __launch_bounds__(256) void k_bin(const int* __restrict__ src,
                                             const int* __restrict__ dst,
                                             int* __restrict__ bcur,
                                             unsigned* __restrict__ binned, int E) {
    __shared__ int hist[16];
    __shared__ int hexcl[16];
    __shared__ int hcur[16];
    __shared__ int gbase[16];
    __shared__ unsigned lout[4096];
    __shared__ unsigned char lb[4096];
    int tid = threadIdx.x;
    int c0 = blockIdx.x * 4096;
    int cnt = min(4096, E - c0);
    if (tid < 16) hist[tid] = 0;
    __syncthreads();
    for (int i = tid; i < cnt; i += 256) {
        int b = dst[c0 + i] >> NPB_SHIFT;
        atomicAdd(&hist[b], 1);
    }
    __syncthreads();
    if (tid == 0) {
        int acc = 0;
        for (int b = 0; b < 16; b++) { hexcl[b] = acc; hcur[b] = acc; acc += hist[b]; }
    }
    __syncthreads();
    if (tid < 16 && hist[tid] > 0) gbase[tid] = atomicAdd(&bcur[tid], hist[tid]);
    for (int i = tid; i < cnt; i += 256) {
        int d = dst[c0 + i];
        int s = src[c0 + i];
        int b = d >> NPB_SHIFT;
        unsigned packed = (unsigned)s | ((unsigned)(d & (NPB - 1)) << 17);
        int p = atomicAdd(&hcur[b], 1);
        lout[p] = packed;
        lb[p] = (unsigned char)b;
    }
    __syncthreads();
    for (int i = tid; i < cnt; i += 256) {
        int b = lb[i];
        binned[gbase[b] + (i - hexcl[b])] = lout[i];
    }
}

// Per-bucket local fill. Bucket b handled by blocks with blockIdx%8 == b%8
// (round-robin XCD heuristic): csr window (512KB) stays in one XCD's L2.
__global__ __launch_bounds__(256) void k_fillL(const unsigned* __restrict__ binned,
                                               const int* __restrict__ bbase,
                                               int* __restrict__ cur,
                                               int* __restrict__ csr, int E, int B) {
    int x = blockIdx.x & 7;   // presumed XCD
    int r = blockIdx.x >> 3;  // rank within XCD, 0..31
    for (int b = x; b < B; b += 8) {
        int bs = bbase[b];
        int be = (b + 1 < B) ? bbase[b + 1] : E;
        int base_node = b << NPB_SHIFT;
        for (int j = bs + r * 256 + threadIdx.x; j < be; j += 32 * 256) {
            unsigned e = binned[j];
            int s = (int)(e & 0x1FFFFu);
            int node = base_node + (int)(e >> 17);
            int pos = atomicAdd(&cur[node], 1);
            csr[pos] = s;
        }
    }
}

// Wave per node. lane = (half h, channel-pair p): one 4B load = 2 channels of
// one of 2 edges -> 2 edges per load instruction. Halves combined at the end.
__global__ __launch_bounds__(256) void k_agg(const int* __restrict__ offs,
                                             const int* __restrict__ cur,
                                             const int* __restrict__ csr,
                                             const unsigned short* __restrict__ xb,
                                             const float* __restrict__ dinv,
                                             unsigned* __restrict__ aggb32, int N) {
    int lane = threadIdx.x & 63;
    int p = lane & 31;   // channel pair (channels 2p, 2p+1)
    int h = lane >> 5;   // half: which edge of a pair this lane gathers
    int wid = (blockIdx.x * 256 + threadIdx.x) >> 6;
    int nw = (gridDim.x * 256) >> 6;

    for (int n = wid; n < N; n += nw) {
        float dn = dinv[n];
        unsigned sv = *(const unsigned*)(xb + (size_t)n * 64 + 2 * p);
        float wself = (h == 0) ? dn : 0.f;  // self-loop counted once
        float accx = bf2f(sv & 0xFFFFu) * wself;
        float accy = bf2f(sv >> 16) * wself;
        int j0 = offs[n];
        int j1 = cur[n];  // == offs[n] + deg[n]
        for (int jb = j0; jb < j1; jb += 64) {
            int cnt = min(64, j1 - jb);
            int idx = 0;
            float w = 0.f;
            if (lane < cnt) {
                idx = csr[jb + lane];
                w = dinv[idx];
            }
            int j = 0;
            for (; j + 8 <= cnt; j += 8) {
                int s0 = __shfl(idx, j + 0 + h), s1 = __shfl(idx, j + 2 + h);
                int s2 = __shfl(idx, j + 4 + h), s3 = __shfl(idx, j + 6 + h);
                float w0 = __shfl(w, j + 0 + h), w1 = __shfl(w, j + 2 + h);
                float w2 = __shfl(w, j + 4 + h), w3 = __shfl(w, j + 6 + h);
                unsigned v0 = *(const unsigned*)(xb + (size_t)s0 * 64 + 2 * p);
                unsigned v1 = *(const unsigned*)(xb + (size_t)s1 * 64 + 2 * p);
                unsigned v2 = *(const unsigned*)(xb + (size_t)s2 * 64 + 2 * p);
                unsigned v3 = *(const unsigned*)(xb + (size_t)s3 * 64 + 2 * p);
                accx = fmaf(w0, bf2f(v0 & 0xFFFFu), accx);
                accy = fmaf(w0, bf2f(v0 >> 16), accy);
                accx = fmaf(w1, bf2f(v1 & 0xFFFFu), accx);
                accy = fmaf(w1, bf2f(v1 >> 16), accy);
                accx = fmaf(w2, bf2f(v2 & 0xFFFFu), accx);
                accy = fmaf(w2, bf2f(v2 >> 16), accy);
                accx = fmaf(w3, bf2f(v3 & 0xFFFFu), accx);
                accy = fmaf(w3, bf2f(v3 >> 16), accy);
            }
            for (; j + 2 <= cnt; j += 2) {
                int s0 = __shfl(idx, j + h);
                float w0 = __shfl(w, j + h);
                unsigned v0 = *(const unsigned*)(xb + (size_t)s0 * 64 + 2 * p);
                accx = fmaf(w0, bf2f(v0 & 0xFFFFu), accx);
                accy = fmaf(w0, bf2f(v0 >> 16), accy);
            }
            if (j < cnt) {  // odd tail: half 0 contributes, half 1 gets w=0
                int s0 = __shfl(idx, j);
                float w0 = __shfl(w, j);
                if (h) w0 = 0.f;
                unsigned v0 = *(const unsigned*)(xb + (size_t)s0 * 64 + 2 * p);
                accx = fmaf(w0, bf2f(v0 & 0xFFFFu), accx);
                accy = fmaf(w0, bf2f(v0 >> 16), accy);
            }
        }
        accx += __shfl_xor(accx, 32);
        accy += __shfl_xor(accy, 32);
        if (h == 0) {
            unsigned o = (unsigned)f2bf(accx * dn) | ((unsigned)f2bf(accy * dn) << 16);
            aggb32[(size_t)n * 32 + p] = o;
        }
    }
}

// out = aggb @ W, thread per row, fp32 accumulate (W staged in LDS).
__global__ __launch_bounds__(256) void k_gemm(const unsigned short* __restrict__ aggb,
                                              const float* __restrict__ W,
                                              float* __restrict__ out, int n) {
    __shared__ float Ws[64 * 64];
    for (int i = threadIdx.x; i < 64 * 64; i += 256) Ws[i] = W[i];
    __syncthreads();
    int r = blockIdx.x * 256 + threadIdx.x;
    if (r >= n) return;

    float a[64];
    const uint4* ap = (const uint4*)(aggb + (size_t)r * 64);
#pragma unroll
    for (int i = 0; i < 8; i++) {
        uint4 q = ap[i];
        a[i * 8 + 0] = bf2f(q.x & 0xFFFFu); a[i * 8 + 1] = bf2f(q.x >> 16);
        a[i * 8 + 2] = bf2f(q.y & 0xFFFFu); a[i * 8 + 3] = bf2f(q.y >> 16);
        a[i * 8 + 4] = bf2f(q.z & 0xFFFFu); a[i * 8 + 5] = bf2f(q.z >> 16);
        a[i * 8 + 6] = bf2f(q.w & 0xFFFFu); a[i * 8 + 7] = bf2f(q.w >> 16);
    }

    float4* op = (float4*)(out + (size_t)r * 64);
#pragma unroll
    for (int c4 = 0; c4 < 16; c4++) {
        float4 acc = {0.f, 0.f, 0.f, 0.f};
#pragma unroll
        for (int k = 0; k < 64; k++) {
            float xv = a[k];
            acc.x = fmaf(xv, Ws[k * 64 + c4 * 4 + 0], acc.x);
            acc.y = fmaf(xv, Ws[k * 64 + c4 * 4 + 1], acc.y);
            acc.z = fmaf(xv, Ws[k * 64 + c4 * 4 + 2], acc.z);
            acc.w = fmaf(xv, Ws[k * 64 + c4 * 4 + 3], acc.w);
        }
        op[c4] = acc;
    }
}

// Per-channel sum & sumsq of out.
__global__ __launch_bounds__(256) void k_stats(const float* __restrict__ out,
                                               float* __restrict__ stats,
                                               int total4) {
    __shared__ float s_sum[64];
    __shared__ float s_sq[64];
    if (threadIdx.x < 64) {
        s_sum[threadIdx.x] = 0.f;
        s_sq[threadIdx.x] = 0.f;
    }
    __syncthreads();

    int idx = blockIdx.x * 256 + threadIdx.x;
    int stride = gridDim.x * 256;
    const float4* p = (const float4*)out;
    float4 sum = {0.f, 0.f, 0.f, 0.f};
    float4 sq = {0.f, 0.f, 0.f, 0.f};
    for (int i = idx; i < total4; i += stride) {
        float4 v = p[i];
        sum.x += v.x; sum.y += v.y; sum.z += v.z; sum.w += v.w;
        sq.x = fmaf(v.x, v.x, sq.x);
        sq.y = fmaf(v.y, v.y, sq.y);
        sq.z = fmaf(v.z, v.z, sq.z);
        sq.w = fmaf(v.w, v.w, sq.w);
    }
#pragma unroll
    for (int off = 16; off < 64; off <<= 1) {
        sum.x += __shfl_xor(sum.x, off);
        sum.y += __shfl_xor(sum.y, off);
        sum.z += __shfl_xor(sum.z, off);
        sum.w += __shfl_xor(sum.w, off);
        sq.x += __shfl_xor(sq.x, off);
        sq.y += __shfl_xor(sq.y, off);
        sq.z += __shfl_xor(sq.z, off);
        sq.w += __shfl_xor(sq.w, off);
    }
    int lane = threadIdx.x & 63;
    if (lane < 16) {
        int cg = (idx * 4) & 63;
        atomicAdd(&s_sum[cg + 0], sum.x);
        atomicAdd(&s_sum[cg + 1], sum.y);
        atomicAdd(&s_sum[cg + 2], sum.z);
        atomicAdd(&s_sum[cg + 3], sum.w);
        atomicAdd(&s_sq[cg + 0], sq.x);
        atomicAdd(&s_sq[cg + 1], sq.y);
        atomicAdd(&s_sq[cg + 2], sq.z);
        atomicAdd(&s_sq[cg + 3], sq.w);
    }
    __syncthreads();
    if (threadIdx.x < 64) {
        atomicAdd(&stats[threadIdx.x], s_sum[threadIdx.x]);
    } else if (threadIdx.x < 128) {
        atomicAdd(&stats[threadIdx.x], s_sq[threadIdx.x - 64]);
    }
}

__global__ void k_bnprep(const float* __restrict__ stats,
                         const float* __restrict__ gamma,
                         const float* __restrict__ beta,
                         float* __restrict__ ss, float invN) {
    int c = threadIdx.x;  // 64 threads
    float mean = stats[c] * invN;
    float var = stats[64 + c] * invN - mean * mean;  // biased var
    float scale = gamma[c] * rsqrtf(var + BN_EPS);
    ss[c] = scale;
    ss[64 + c] = beta[c] - mean * scale;
}

__global__ __launch_bounds__(256) void k_bn(float* __restrict__ out,
                                            const float* __restrict__ ss,
                                            int total4) {
    int idx = blockIdx.x * 256 + threadIdx.x;
    int stride = gridDim.x * 256;
    int cg = (idx * 4) & 63;
    float sc0 = ss[cg + 0], sc1 = ss[cg + 1], sc2 = ss[cg + 2], sc3 = ss[cg + 3];
    float sh0 = ss[64 + cg + 0], sh1 = ss[64 + cg + 1];
    float sh2 = ss[64 + cg + 2], sh3 = ss[64 + cg + 3];
    float4* p = (float4*)out;
    for (int i = idx; i < total4; i += stride) {
        float4 v = p[i];
        v.x = fmaxf(fmaf(v.x, sc0, sh0), 0.f);
        v.y = fmaxf(fmaf(v.y, sc1, sh1), 0.f);
        v.z = fmaxf(fmaf(v.z, sc2, sh2), 0.f);
        v.w = fmaxf(fmaf(v.w, sc3, sh3), 0.f);
        p[i] = v;
    }
}

extern "C" void kernel_launch(void* const* d_in, const int* in_sizes, int n_in,
                              void* d_out, int out_size, void* d_ws, size_t ws_size,
                              hipStream_t stream) {
    const float* x = (const float*)d_in[0];
    const int* ei = (const int*)d_in[1];
    const float* W = (const float*)d_in[2];
    // d_in[3] = bias: cancels inside BatchNorm, unused.
    const float* gamma = (const float*)d_in[4];
    const float* beta = (const float*)d_in[5];
    float* out = (float*)d_out;

    const int N = in_sizes[0] / 64;
    const int E = in_sizes[1] / 2;
    const int* src = ei;
    const int* dst = ei + E;
    const int NB = (N + 255) / 256;          // 391 (<=512 for k_scan2)
    const int B = (N + NPB - 1) >> NPB_SHIFT;  // 13 buckets

    char* ws = (char*)d_ws;
    int* deg = (int*)ws;                                    // 4N
    float* stats = (float*)(ws + (size_t)4 * N);            // 512 B
    float* ss = (float*)(ws + (size_t)4 * N + 512);         // 512 B
    int* part = (int*)(ws + (size_t)4 * N + 1024);          // 2 KB
    int* base = (int*)(ws + (size_t)4 * N + 3072);          // 2 KB
    int* bbase = (int*)(ws + (size_t)4 * N + 5120);         // 64 B
    int* bcur = (int*)(ws + (size_t)4 * N + 5184);          // 64 B
    int* offs = (int*)(ws + (size_t)4 * N + 5376);          // 4N
    int* cur = (int*)(ws + (size_t)8 * N + 5376);           // 4N
    float* dinv = (float*)(ws + (size_t)12 * N + 5376);     // 4N
    unsigned short* xb = (unsigned short*)(ws + (size_t)16 * N + 5376);   // 128N
    unsigned short* aggb = (unsigned short*)(ws + (size_t)144 * N + 5376);// 128N
    unsigned* binned = (unsigned*)(ws + (size_t)272 * N + 5376);          // 4E
    int* csr = (int*)(ws + (size_t)272 * N + (size_t)4 * E + 5376);       // 4E

    // zero deg + stats (contiguous)
    hipMemsetAsync(deg, 0, (size_t)4 * N + 512, stream);

    int n4 = N * 16;
    int preN = (E > n4) ? E : n4;
    k_pre<<<(preN + 255) / 256, 256, 0, stream>>>(x, dst, deg, xb, E, n4);
    k_scan1<<<NB, 256, 0, stream>>>(deg, part, N);
    k_scan2<<<1, 512, 0, stream>>>(part, base, NB);
    k_scan3<<<NB, 256, 0, stream>>>(deg, base, offs, cur, dinv, bbase, bcur, N);
    k_bin<<<(E + 4095) / 4096, 256, 0, stream>>>(src, dst, bcur, binned, E);
    k_fillL<<<256, 256, 0, stream>>>(binned, bbase, cur, csr, E, B);
    k_agg<<<2048, 256, 0, stream>>>(offs, cur, csr, xb, dinv, (unsigned*)aggb, N);
    k_gemm<<<(N + 255) / 256, 256, 0, stream>>>(aggb, W, out, N);
    k_stats<<<1024, 256, 0, stream>>>(out, stats, N * 16);
    k_bnprep<<<1, 64, 0, stream>>>(stats, gamma, beta, ss, 1.0f / (float)N);
    k_bn<<<1024, 256, 0, stream>>>(out, ss, N * 16);
}